// Round 2
// baseline (1403.584 us; speedup 1.0000x reference)
//
#include <hip/hip_runtime.h>
#include <math.h>

#define T 8192
#define E 64
#define CAP 320
#define NCHUNK 256
#define CHUNK 32      // tokens per chunk (one block per chunk in pass1/scatter)

// ---- workspace layout (4-byte units) ----
#define WS_TOP1   0
#define WS_TOP2   (WS_TOP1 + T)
#define WS_P1     (WS_TOP2 + T)
#define WS_P2     (WS_P1 + T)
#define WS_CNT1   (WS_P2 + T)                 // NCHUNK*E ints
#define WS_CNT2   (WS_CNT1 + NCHUNK*E)
#define WS_BASE1  (WS_CNT2 + NCHUNK*E)
#define WS_BASE2  (WS_BASE1 + NCHUNK*E)
#define WS_TOT1   (WS_BASE2 + NCHUNK*E)       // E ints
#define WS_PSUM   (WS_TOT1 + E)               // E floats (atomic acc)
#define WS_ZSUM   (WS_PSUM + E)               // 1 float  (atomic acc)
#define WS_END    (WS_ZSUM + 1)

// output layout (float32 elements)
#define OUT_UC    0
#define OUT_CB    ((size_t)64)
#define OUT_SEC   (OUT_CB + (size_t)T * E * CAP)
#define OUT_AUX   (OUT_SEC + (size_t)T * E * CAP)
#define OUT_Z     (OUT_AUX + 1)
#define OUT_N     (OUT_Z + 1)                 // 335,544,386 floats total

// Zero the entire output with wide stores (the runtime fill kernel moved 4x
// the traffic: 5.37GB written for a 1.34GB buffer). Also zeroes the ws
// atomic accumulators so no separate memset dispatch is needed.
__global__ __launch_bounds__(256) void zero_out(float* __restrict__ out,
                                                float* __restrict__ wsf) {
    const size_t M4 = OUT_N / 4;              // float4 count (floor)
    float4* __restrict__ out4 = (float4*)out;
    size_t idx = (size_t)blockIdx.x * 256 + threadIdx.x;
    const size_t stride = (size_t)gridDim.x * 256;
    const float4 z = make_float4(0.f, 0.f, 0.f, 0.f);
    for (; idx < M4; idx += stride) out4[idx] = z;
    if (blockIdx.x == 0) {
        if (threadIdx.x < OUT_N - M4 * 4) out[M4 * 4 + threadIdx.x] = 0.f;
        if (threadIdx.x < E + 1) wsf[WS_PSUM + threadIdx.x] = 0.f;
    }
}

__global__ __launch_bounds__(256) void router_pass1(const float* __restrict__ in,
                                                    int* __restrict__ wsi,
                                                    float* __restrict__ wsf) {
    const int chunk = blockIdx.x;
    const int wave  = threadIdx.x >> 6;
    const int lane  = threadIdx.x & 63;

    int*   top1 = wsi + WS_TOP1;
    int*   top2 = wsi + WS_TOP2;
    float* p1a  = wsf + WS_P1;
    float* p2a  = wsf + WS_P2;

    float probsum_local = 0.f;   // lane e accumulates prob mass of expert e
    float z_local = 0.f;
    int   c1_local = 0, c2_local = 0;

    #pragma unroll
    for (int i = 0; i < CHUNK / 4; ++i) {     // 8 tokens per wave
        const int t = chunk * CHUNK + wave * (CHUNK / 4) + i;
        float x = in[(size_t)t * E + lane];

        // wave max
        float m = x;
        #pragma unroll
        for (int s = 32; s >= 1; s >>= 1) m = fmaxf(m, __shfl_xor(m, s));

        float ex = expf(x - m);
        float ssum = ex;
        #pragma unroll
        for (int s = 32; s >= 1; s >>= 1) ssum += __shfl_xor(ssum, s);

        float p   = ex / ssum;
        float lse = m + logf(ssum);
        z_local += lse * lse;                 // identical on all lanes; lane0's used
        probsum_local += p;

        // argmax over p, tie-break lowest index (matches jnp.argmax)
        float bv = p; int bi = lane;
        #pragma unroll
        for (int s = 32; s >= 1; s >>= 1) {
            float ov = __shfl_xor(bv, s);
            int   oi = __shfl_xor(bi, s);
            if (ov > bv || (ov == bv && oi < bi)) { bv = ov; bi = oi; }
        }
        const int e1 = bi; const float p1v = bv;

        // second argmax with top1 masked to -inf
        float pm = (lane == e1) ? -INFINITY : p;
        float bv2 = pm; int bi2 = lane;
        #pragma unroll
        for (int s = 32; s >= 1; s >>= 1) {
            float ov = __shfl_xor(bv2, s);
            int   oi = __shfl_xor(bi2, s);
            if (ov > bv2 || (ov == bv2 && oi < bi2)) { bv2 = ov; bi2 = oi; }
        }
        const int e2 = bi2; const float p2v = bv2;

        c1_local += (lane == e1);
        c2_local += (lane == e2);

        if (lane == 0) {
            top1[t] = e1; top2[t] = e2;
            p1a[t] = p1v; p2a[t] = p2v;
        }
    }

    __shared__ float s_ps[4][64];
    __shared__ int   s_c1[4][64];
    __shared__ int   s_c2[4][64];
    __shared__ float s_z[4];
    s_ps[wave][lane] = probsum_local;
    s_c1[wave][lane] = c1_local;
    s_c2[wave][lane] = c2_local;
    if (lane == 0) s_z[wave] = z_local;
    __syncthreads();

    if (wave == 0) {
        float ps = s_ps[0][lane] + s_ps[1][lane] + s_ps[2][lane] + s_ps[3][lane];
        int   a1 = s_c1[0][lane] + s_c1[1][lane] + s_c1[2][lane] + s_c1[3][lane];
        int   a2 = s_c2[0][lane] + s_c2[1][lane] + s_c2[2][lane] + s_c2[3][lane];
        wsi[WS_CNT1 + chunk * E + lane] = a1;
        wsi[WS_CNT2 + chunk * E + lane] = a2;
        atomicAdd(&wsf[WS_PSUM + lane], ps);
        if (lane == 0) atomicAdd(&wsf[WS_ZSUM], s_z[0] + s_z[1] + s_z[2] + s_z[3]);
    }
}

__global__ __launch_bounds__(64) void router_scan(int* __restrict__ wsi,
                                                  float* __restrict__ wsf,
                                                  float* __restrict__ out) {
    const int e = threadIdx.x;   // one wave, lane = expert
    int acc1 = 0, acc2 = 0;
    for (int c = 0; c < NCHUNK; ++c) {
        wsi[WS_BASE1 + c * E + e] = acc1;
        acc1 += wsi[WS_CNT1 + c * E + e];
        wsi[WS_BASE2 + c * E + e] = acc2;
        acc2 += wsi[WS_CNT2 + c * E + e];
    }
    wsi[WS_TOT1 + e] = acc1;

    const int cnt = acc1 + acc2;
    out[OUT_UC + e] = (float)(cnt < CAP ? cnt : CAP);

    float aux = (float)cnt * wsf[WS_PSUM + e];
    #pragma unroll
    for (int s = 32; s >= 1; s >>= 1) aux += __shfl_xor(aux, s);
    if (e == 0) {
        // aux_loss = E * sum_e(cnt*psum) / T^2 = sum / 1048576
        out[OUT_AUX] = aux * (float)E / ((float)T * (float)T);
        out[OUT_Z]   = wsf[WS_ZSUM] / (float)T;
    }
}

__global__ __launch_bounds__(64) void router_scatter(const int* __restrict__ wsi,
                                                     const float* __restrict__ wsf,
                                                     float* __restrict__ out) {
    const int b = blockIdx.x;    // chunk
    const int e = threadIdx.x;   // lane = expert

    const int* top1 = wsi + WS_TOP1;
    const int* top2 = wsi + WS_TOP2;
    const float* p1a = wsf + WS_P1;
    const float* p2a = wsf + WS_P2;

    float* cb  = out + OUT_CB;
    float* sec = out + OUT_SEC;

    int c1 = wsi[WS_BASE1 + b * E + e];
    int r2 = wsi[WS_BASE2 + b * E + e] + wsi[WS_TOT1 + e];

    for (int i = 0; i < CHUNK; ++i) {
        const int t = b * CHUNK + i;
        const int e1 = top1[t];
        const int e2 = top2[t];
        if (e == e1) {
            if (c1 < CAP) {
                const size_t off = ((size_t)t * E + e) * CAP + c1;
                cb[off]  = p1a[t];
                sec[off] = 1.0f;
            }
            c1++;
        }
        if (e == e2) {
            if (r2 < CAP) {
                const size_t off = ((size_t)t * E + e) * CAP + r2;
                cb[off]  = p2a[t];
                sec[off] = 1.0f;
            }
            r2++;
        }
    }
}

extern "C" void kernel_launch(void* const* d_in, const int* in_sizes, int n_in,
                              void* d_out, int out_size, void* d_ws, size_t ws_size,
                              hipStream_t stream) {
    const float* in = (const float*)d_in[0];
    float* out = (float*)d_out;
    int*   wsi = (int*)d_ws;
    float* wsf = (float*)d_ws;

    // Zero entire output (poisoned 0xAA before every call) + ws accumulators.
    zero_out<<<2048, 256, 0, stream>>>(out, wsf);

    router_pass1<<<NCHUNK, 256, 0, stream>>>(in, wsi, wsf);
    router_scan<<<1, 64, 0, stream>>>(wsi, wsf, out);
    router_scatter<<<NCHUNK, 64, 0, stream>>>(wsi, wsf, out);
}

// Round 3
// 1315.294 us; speedup vs baseline: 1.0671x; 1.0671x over previous
//
#include <hip/hip_runtime.h>
#include <math.h>

#define T 8192
#define E 64
#define CAP 320
#define NCHUNK 256
#define CHUNK 32      // tokens per chunk (one block per chunk in pass1/scatter)
#define NQ 16         // scan: waves; each wave scans NCHUNK/NQ chunks

// ---- workspace layout (4-byte units) ----
#define WS_TOP1   0
#define WS_TOP2   (WS_TOP1 + T)
#define WS_P1     (WS_TOP2 + T)
#define WS_P2     (WS_P1 + T)
#define WS_CNT1   (WS_P2 + T)                 // NCHUNK*E ints
#define WS_CNT2   (WS_CNT1 + NCHUNK*E)
#define WS_BASE1  (WS_CNT2 + NCHUNK*E)
#define WS_BASE2  (WS_BASE1 + NCHUNK*E)
#define WS_TOT1   (WS_BASE2 + NCHUNK*E)       // E ints
#define WS_PSUM   (WS_TOT1 + E)               // E floats (atomic acc)
#define WS_ZSUM   (WS_PSUM + E)               // 1 float  (atomic acc)
#define WS_END    (WS_ZSUM + 1)

// output layout (float32 elements)
#define OUT_UC    0
#define OUT_CB    ((size_t)64)
#define OUT_SEC   (OUT_CB + (size_t)T * E * CAP)
#define OUT_AUX   (OUT_SEC + (size_t)T * E * CAP)
#define OUT_Z     (OUT_AUX + 1)
#define OUT_N     (OUT_Z + 1)

__global__ __launch_bounds__(256) void router_pass1(const float* __restrict__ in,
                                                    int* __restrict__ wsi,
                                                    float* __restrict__ wsf) {
    const int chunk = blockIdx.x;
    const int wave  = threadIdx.x >> 6;
    const int lane  = threadIdx.x & 63;

    int*   top1 = wsi + WS_TOP1;
    int*   top2 = wsi + WS_TOP2;
    float* p1a  = wsf + WS_P1;
    float* p2a  = wsf + WS_P2;

    float probsum_local = 0.f;   // lane e accumulates prob mass of expert e
    float z_local = 0.f;
    int   c1_local = 0, c2_local = 0;

    #pragma unroll
    for (int i = 0; i < CHUNK / 4; ++i) {     // 8 tokens per wave
        const int t = chunk * CHUNK + wave * (CHUNK / 4) + i;
        float x = in[(size_t)t * E + lane];

        // wave max
        float m = x;
        #pragma unroll
        for (int s = 32; s >= 1; s >>= 1) m = fmaxf(m, __shfl_xor(m, s));

        float ex = expf(x - m);
        float ssum = ex;
        #pragma unroll
        for (int s = 32; s >= 1; s >>= 1) ssum += __shfl_xor(ssum, s);

        float p   = ex / ssum;
        float lse = m + logf(ssum);
        z_local += lse * lse;                 // identical on all lanes; lane0's used
        probsum_local += p;

        // argmax over p, tie-break lowest index (matches jnp.argmax)
        float bv = p; int bi = lane;
        #pragma unroll
        for (int s = 32; s >= 1; s >>= 1) {
            float ov = __shfl_xor(bv, s);
            int   oi = __shfl_xor(bi, s);
            if (ov > bv || (ov == bv && oi < bi)) { bv = ov; bi = oi; }
        }
        const int e1 = bi; const float p1v = bv;

        // second argmax with top1 masked to -inf
        float pm = (lane == e1) ? -INFINITY : p;
        float bv2 = pm; int bi2 = lane;
        #pragma unroll
        for (int s = 32; s >= 1; s >>= 1) {
            float ov = __shfl_xor(bv2, s);
            int   oi = __shfl_xor(bi2, s);
            if (ov > bv2 || (ov == bv2 && oi < bi2)) { bv2 = ov; bi2 = oi; }
        }
        const int e2 = bi2; const float p2v = bv2;

        c1_local += (lane == e1);
        c2_local += (lane == e2);

        if (lane == 0) {
            top1[t] = e1; top2[t] = e2;
            p1a[t] = p1v; p2a[t] = p2v;
        }
    }

    __shared__ float s_ps[4][64];
    __shared__ int   s_c1[4][64];
    __shared__ int   s_c2[4][64];
    __shared__ float s_z[4];
    s_ps[wave][lane] = probsum_local;
    s_c1[wave][lane] = c1_local;
    s_c2[wave][lane] = c2_local;
    if (lane == 0) s_z[wave] = z_local;
    __syncthreads();

    if (wave == 0) {
        float ps = s_ps[0][lane] + s_ps[1][lane] + s_ps[2][lane] + s_ps[3][lane];
        int   a1 = s_c1[0][lane] + s_c1[1][lane] + s_c1[2][lane] + s_c1[3][lane];
        int   a2 = s_c2[0][lane] + s_c2[1][lane] + s_c2[2][lane] + s_c2[3][lane];
        wsi[WS_CNT1 + chunk * E + lane] = a1;
        wsi[WS_CNT2 + chunk * E + lane] = a2;
        atomicAdd(&wsf[WS_PSUM + lane], ps);
        if (lane == 0) atomicAdd(&wsf[WS_ZSUM], s_z[0] + s_z[1] + s_z[2] + s_z[3]);
    }
}

// Parallel chunk-scan: 16 waves; wave q owns chunks [16q, 16q+16), lane = expert.
// Serial depth 256 -> 16+16 (was the dominant compute cost: single-wave walk
// over cross-XCD data at ~900cyc/load).
__global__ __launch_bounds__(1024) void router_scan(int* __restrict__ wsi,
                                                    float* __restrict__ wsf,
                                                    float* __restrict__ out) {
    const int e = threadIdx.x & 63;
    const int q = threadIdx.x >> 6;           // wave id 0..15
    const int C0 = q * (NCHUNK / NQ);

    __shared__ int s1[NQ][E];
    __shared__ int s2[NQ][E];

    // pass A: per-quarter sums
    int sum1 = 0, sum2 = 0;
    #pragma unroll
    for (int c = C0; c < C0 + NCHUNK / NQ; ++c) {
        sum1 += wsi[WS_CNT1 + c * E + e];
        sum2 += wsi[WS_CNT2 + c * E + e];
    }
    s1[q][e] = sum1; s2[q][e] = sum2;
    __syncthreads();

    // offsets for this quarter + grand totals
    int off1 = 0, off2 = 0, tot1 = 0, tot2 = 0;
    #pragma unroll
    for (int qq = 0; qq < NQ; ++qq) {
        int v1 = s1[qq][e], v2 = s2[qq][e];
        if (qq < q) { off1 += v1; off2 += v2; }
        tot1 += v1; tot2 += v2;
    }

    // pass B: write exclusive bases (L2-warm re-read)
    int acc1 = off1, acc2 = off2;
    #pragma unroll
    for (int c = C0; c < C0 + NCHUNK / NQ; ++c) {
        wsi[WS_BASE1 + c * E + e] = acc1;
        acc1 += wsi[WS_CNT1 + c * E + e];
        wsi[WS_BASE2 + c * E + e] = acc2;
        acc2 += wsi[WS_CNT2 + c * E + e];
    }

    if (q == 0) {
        wsi[WS_TOT1 + e] = tot1;
        const int cnt = tot1 + tot2;
        out[OUT_UC + e] = (float)(cnt < CAP ? cnt : CAP);

        float aux = (float)cnt * wsf[WS_PSUM + e];
        #pragma unroll
        for (int s = 32; s >= 1; s >>= 1) aux += __shfl_xor(aux, s);
        if (e == 0) {
            // aux_loss = E * sum_e(cnt*psum) / T^2
            out[OUT_AUX] = aux * (float)E / ((float)T * (float)T);
            out[OUT_Z]   = wsf[WS_ZSUM] / (float)T;
        }
    }
}

__global__ __launch_bounds__(64) void router_scatter(const int* __restrict__ wsi,
                                                     const float* __restrict__ wsf,
                                                     float* __restrict__ out) {
    const int b = blockIdx.x;    // chunk
    const int e = threadIdx.x;   // lane = expert

    const int* top1 = wsi + WS_TOP1;
    const int* top2 = wsi + WS_TOP2;
    const float* p1a = wsf + WS_P1;
    const float* p2a = wsf + WS_P2;

    float* cb  = out + OUT_CB;
    float* sec = out + OUT_SEC;

    int c1 = wsi[WS_BASE1 + b * E + e];
    int r2 = wsi[WS_BASE2 + b * E + e] + wsi[WS_TOT1 + e];

    for (int i = 0; i < CHUNK; ++i) {
        const int t = b * CHUNK + i;
        const int e1 = top1[t];
        const int e2 = top2[t];
        if (e == e1) {
            if (c1 < CAP) {
                const size_t off = ((size_t)t * E + e) * CAP + c1;
                cb[off]  = p1a[t];
                sec[off] = 1.0f;
            }
            c1++;
        }
        if (e == e2) {
            if (r2 < CAP) {
                const size_t off = ((size_t)t * E + e) * CAP + r2;
                cb[off]  = p2a[t];
                sec[off] = 1.0f;
            }
            r2++;
        }
    }
}

extern "C" void kernel_launch(void* const* d_in, const int* in_sizes, int n_in,
                              void* d_out, int out_size, void* d_ws, size_t ws_size,
                              hipStream_t stream) {
    const float* in = (const float*)d_in[0];
    float* out = (float*)d_out;
    int*   wsi = (int*)d_ws;
    float* wsf = (float*)d_ws;

    // Runtime 0-fill proved faster than a hand zero kernel (R1 vs R2 A/B).
    hipMemsetAsync(d_out, 0, (size_t)out_size * sizeof(float), stream);
    // Zero only the atomic accumulators in ws (probsum + zsum).
    hipMemsetAsync((char*)d_ws + (size_t)WS_PSUM * 4, 0, (E + 1) * 4, stream);

    router_pass1<<<NCHUNK, 256, 0, stream>>>(in, wsi, wsf);
    router_scan<<<1, 1024, 0, stream>>>(wsi, wsf, out);
    router_scatter<<<NCHUNK, 64, 0, stream>>>(wsi, wsf, out);
}